// Round 2
// baseline (155.870 us; speedup 1.0000x reference)
//
#include <hip/hip_runtime.h>

// CritiGraph fused loss kernel, MI355X (gfx950). Round 2.
//
//  * voc_emb is DEAD in the reference (eu_val[:,64:] never used) -> never read.
//  * cos_similarity(c1,c2) = sgn * (clz(|c1|^|c2| + 1)/16 - 1), sgn = sign(c1)*sign(c2).
//    Packing (sign<<31)|abs lets one XOR produce both sign product (bit31) and abs-xor.
//  * loss_dyn_dyn = kl + lse_s(ct) - sum_s p_eu*ct ; loss_dyn_sta = lse_v(20ct) - 20ct[tar].
//  * All logits pre-scaled by log2e -> v_exp_f32/v_log_f32 directly (no mul inside exp).
//  * Round-invariant tables (pos packed, base, p_eu) preloaded to registers: the
//    65-round inner loop is a pure VALU stream, no DS reads.
//  * Grid = 2 blocks per t (c-halves) for 4 blocks/CU occupancy.

#define Tn   512
#define NC   65
#define TPd  8
#define NTn  64
#define KV   128
#define Sn   192
#define Dn   256

#define LOG2E 1.44269504088896340736f
#define LN2   0.69314718055994530942f
// clz -> cos fma constants, scale folded in:  cos*scale = fma(fclz, scale/16, -scale)
#define K1D (0.0625f * 0.125f * LOG2E)
#define K0D (-0.125f * LOG2E)
#define K1S (0.0625f * 2.5f * LOG2E)
#define K0S (-2.5f * LOG2E)

__device__ __forceinline__ float exp2_fast(float x) {
#if __has_builtin(__builtin_amdgcn_exp2f)
    return __builtin_amdgcn_exp2f(x);
#else
    return exp2f(x);
#endif
}

__global__ __launch_bounds__(256, 4) void critigraph_kernel(
    const int*   __restrict__ cur_tar,   // (T)
    const int*   __restrict__ cnc_loc,   // (T, NC, TP)
    const int*   __restrict__ sta_loc,   // (T, TP)
    const int*   __restrict__ ttn_loc,   // (T, NT, TP)
    const int*   __restrict__ voc_loc,   // (T, KV, TP)
    const float* __restrict__ sta_emb,   // (T, D)
    const float* __restrict__ ttn_emb,   // (T, NT, D)
    float*       __restrict__ out)       // [dd: T*NC*TP][ds: T*NC*TP]
{
    __shared__ int2  s_ab[Sn * TPd];     // {packed pos_loc, bits(base2)}; base2 = (csum-sp)*scale*log2e
    __shared__ float s_csum[Sn];
    __shared__ float s_peu[NTn];
    __shared__ float s_eu[NTn];
    __shared__ int   s_cnc[NC * TPd];    // packed cnc_loc
    __shared__ int   s_sta[TPd];
    __shared__ float s_dotbase[TPd];     // sum_s p_eu[s]*base2_dyn[s,p]
    __shared__ float s_kl;

    const int bx   = blockIdx.x;
    const int t    = bx >> 1;
    const int half = bx & 1;
    const int c0   = half ? 33 : 0;
    const int c1   = half ? NC : 33;

    const int tid  = threadIdx.x;
    const int lane = tid & 63;
    const int wv   = tid >> 6;

    // ---- A: stage sta_loc / cnc_loc (packed) ----
    if (tid < TPd) {
        int v = sta_loc[t * TPd + tid];
        s_sta[tid] = (v < 0) ? (int)(0x80000000u | (unsigned)(-v)) : v;
    }
    for (int i = tid; i < NC * TPd; i += 256) {
        int v = cnc_loc[t * NC * TPd + i];
        s_cnc[i] = (v < 0) ? (int)(0x80000000u | (unsigned)(-v)) : v;
    }
    __syncthreads();

    // ---- B: pos packed + cos_sp (cos_sp temporarily in s_ab[].y) ----
    for (int i = tid; i < Sn * TPd; i += 256) {
        int s = i >> 3;
        int v = (s < NTn) ? ttn_loc[t * NTn * TPd + i]
                          : voc_loc[t * KV * TPd + (i - NTn * TPd)];
        int packed = (v < 0) ? (int)(0x80000000u | (unsigned)(-v)) : v;
        int   y    = packed ^ s_sta[i & 7];
        int   x    = (y & 0x7fffffff) + 1;
        float fclz = (float)__clz(x);
        float c    = fmaf(fclz, 0.0625f, -1.0f);           // 1 - e/16
        c = __int_as_float(__float_as_int(c) ^ (y & 0x80000000));
        s_ab[i] = make_int2(packed, __float_as_int(c));
    }
    //      eu = sta_emb . ttn_emb (one wave per row, lane-per-float4, coalesced)
    {
        const float4* a4 = (const float4*)(sta_emb + (size_t)t * Dn);
        float4 a = a4[lane];
        for (int s = wv; s < NTn; s += 4) {
            const float4* b4 = (const float4*)(ttn_emb + ((size_t)t * NTn + s) * Dn);
            float4 b = b4[lane];
            float d = a.x * b.x + a.y * b.y + a.z * b.z + a.w * b.w;
            #pragma unroll
            for (int m = 1; m < 64; m <<= 1) d += __shfl_xor(d, m);
            if (lane == 0) s_eu[s] = d;                    // 20*TEMP = 1.0
        }
    }
    __syncthreads();

    // ---- C: cos_sum per s ----
    if (tid < Sn) {
        float a = 0.f;
        #pragma unroll
        for (int p = 0; p < TPd; ++p) a += __int_as_float(s_ab[tid * TPd + p].y);
        s_csum[tid] = a;
    }
    __syncthreads();

    // ---- D: rewrite .y with scaled base2; softmax over eu (wave 0) ----
    for (int i = tid; i < Sn * TPd; i += 256) {
        int s = i >> 3;
        float sc = (s < NTn) ? (0.125f * LOG2E) : (2.5f * LOG2E);
        float sp = __int_as_float(s_ab[i].y);
        s_ab[i].y = __float_as_int((s_csum[s] - sp) * sc);
    }
    if (tid < 64) {
        float e  = s_eu[tid];
        float mx = e;
        #pragma unroll
        for (int m = 1; m < 64; m <<= 1) mx = fmaxf(mx, __shfl_xor(mx, m));
        float ex = __expf(e - mx);
        float z  = ex;
        #pragma unroll
        for (int m = 1; m < 64; m <<= 1) z += __shfl_xor(z, m);
        float pe = ex / z;
        s_peu[tid] = pe;
        float kls = pe * ((e - mx) - __logf(z));
        #pragma unroll
        for (int m = 1; m < 64; m <<= 1) kls += __shfl_xor(kls, m);
        if (tid == 0) s_kl = kls;
    }
    __syncthreads();

    // ---- E: dotbase[p] = sum_s p_eu[s]*base2_dyn[s,p]  (wave 0) ----
    if (tid < 64) {
        int g = tid & 7, j = tid >> 3;
        float a = 0.f;
        #pragma unroll
        for (int k = 0; k < 8; ++k) {
            int s = j * 8 + k;
            a = fmaf(s_peu[s], __int_as_float(s_ab[s * TPd + g].y), a);
        }
        #pragma unroll
        for (int m = 8; m < 64; m <<= 1) a += __shfl_xor(a, m);
        if (tid < TPd) s_dotbase[g] = a;
    }
    __syncthreads();

    // ---- F: phase B. 8-lane group per (c,p); round-invariant tables in registers ----
    const int g   = lane >> 3;   // p
    const int sub = lane & 7;    // s-slice within group
    const int tar = cur_tar[t];

    float rpeu[8];
    int2  rdyn[8];
    int2  rsta[16];
    #pragma unroll
    for (int k = 0; k < 8; ++k) {
        rpeu[k] = s_peu[sub + 8 * k];
        rdyn[k] = s_ab[(sub + 8 * k) * TPd + g];
    }
    #pragma unroll
    for (int k = 0; k < 16; ++k) rsta[k] = s_ab[(NTn + sub + 8 * k) * TPd + g];
    const int2  rtar = s_ab[(NTn + tar) * TPd + g];
    const float dotb = s_dotbase[g];
    const float kl   = s_kl;

    float* out_dd = out + (size_t)t * NC * TPd;
    float* out_ds = out + (size_t)Tn * NC * TPd + (size_t)t * NC * TPd;

    for (int r = c0 + wv; r < c1; r += 4) {                // r == c
        const int acnc = s_cnc[r * TPd + g];

        float sum = 0.f, dotcc = 0.f;
        #pragma unroll
        for (int k = 0; k < 8; ++k) {
            int   y    = rdyn[k].x ^ acnc;
            int   x    = (y & 0x7fffffff) + 1;
            float fclz = (float)__clz(x);
            float cc   = fmaf(fclz, K1D, K0D);             // cos * 0.125 * log2e
            cc = __int_as_float(__float_as_int(cc) ^ (y & 0x80000000));
            sum += exp2_fast(__int_as_float(rdyn[k].y) + cc);
            dotcc = fmaf(rpeu[k], cc, dotcc);
        }

        float sum2a = 0.f, sum2b = 0.f;
        #pragma unroll
        for (int k = 0; k < 16; ++k) {
            int   y    = rsta[k].x ^ acnc;
            int   x    = (y & 0x7fffffff) + 1;
            float fclz = (float)__clz(x);
            float cc   = fmaf(fclz, K1S, K0S);             // cos * 2.5 * log2e
            cc = __int_as_float(__float_as_int(cc) ^ (y & 0x80000000));
            float e = exp2_fast(__int_as_float(rsta[k].y) + cc);
            if (k & 1) sum2b += e; else sum2a += e;
        }
        float sum2 = sum2a + sum2b;

        #pragma unroll
        for (int m = 1; m < 8; m <<= 1) {
            sum   += __shfl_xor(sum, m);
            dotcc += __shfl_xor(dotcc, m);
            sum2  += __shfl_xor(sum2, m);
        }

        if (sub == 0) {
            int   y    = rtar.x ^ acnc;
            int   x    = (y & 0x7fffffff) + 1;
            float fclz = (float)__clz(x);
            float cc   = fmaf(fclz, K1S, K0S);
            cc = __int_as_float(__float_as_int(cc) ^ (y & 0x80000000));
            float tgt2 = __int_as_float(rtar.y) + cc;      // 20ct[tar] * log2e
            out_dd[r * TPd + g] = kl + LN2 * (__log2f(sum) - (dotb + dotcc));
            out_ds[r * TPd + g] = LN2 * (__log2f(sum2) - tgt2);
        }
    }
}

extern "C" void kernel_launch(void* const* d_in, const int* in_sizes, int n_in,
                              void* d_out, int out_size, void* d_ws, size_t ws_size,
                              hipStream_t stream) {
    (void)in_sizes; (void)n_in; (void)d_ws; (void)ws_size; (void)out_size;
    const int*   cur_tar = (const int*)  d_in[0];
    const int*   cnc_loc = (const int*)  d_in[1];
    const int*   sta_loc = (const int*)  d_in[2];
    const int*   ttn_loc = (const int*)  d_in[3];
    const int*   voc_loc = (const int*)  d_in[4];
    const float* sta_emb = (const float*)d_in[5];
    const float* ttn_emb = (const float*)d_in[6];
    // d_in[7] (voc_emb) intentionally unused: it only feeds eu_val[:,64:], which the
    // reference discards.
    critigraph_kernel<<<Tn * 2, 256, 0, stream>>>(cur_tar, cnc_loc, sta_loc, ttn_loc,
                                                  voc_loc, sta_emb, ttn_emb, (float*)d_out);
}

// Round 3
// 142.848 us; speedup vs baseline: 1.0912x; 1.0912x over previous
//
#include <hip/hip_runtime.h>

// CritiGraph fused loss kernel, MI355X (gfx950). Round 3.
//
//  * voc_emb is DEAD in the reference (eu_val[:,64:] never used) -> never read.
//  * cos_similarity(c1,c2) = sgn * (clz(|c1|^|c2|+1)/16 - 1); pack (sign<<31)|abs so one
//    XOR yields sign product (bit31) and abs-xor (low bits). Sign applied by xor on cc
//    (flips sign regardless of cc's own sign - required since cos magnitude can be -1/16).
//  * loss_dyn_dyn = kl + lse_s(ct) - sum_s p_eu*ct ; loss_dyn_sta = lse_v(20ct) - 20ct[tar].
//  * log2-domain throughout (LOG2E folded into tables/constants) -> raw v_exp_f32/v_log_f32.
//  * Round-3 structure: thread-per-(c,p) pair, 2 pairs per thread (c, c+32) sharing one
//    LDS stream -> ZERO shuffles in the hot loop; sums are thread-local scalars.
//  * Hot-loop LDS reads are wave-uniform in s: 8 distinct addresses x 8-lane broadcast,
//    int4 dyn table spans all 32 banks -> conflict-free.
//  * eu dot: 4 threads/row, 16 independent float4 loads each (1 memory round trip),
//    2-shuffle reduce -- replaces 16 serial row-reductions.

#define Tn   512
#define NC   65
#define TPd  8
#define NTn  64
#define KV   128
#define Sn   192
#define Dn   256
#define OUT1 (Tn * NC * TPd)

#define LOG2E 1.44269504088896340736f
#define LN2   0.69314718055994530942f
// cc = fma(clz, scale/16*LOG2E, -scale*LOG2E)  == cos*scale*LOG2E (sign applied after)
#define K1D (0.0625f * 0.125f * LOG2E)
#define K0D (-0.125f * LOG2E)
#define K1S (0.0625f * 2.5f * LOG2E)
#define K0S (-2.5f * LOG2E)

__device__ __forceinline__ float exp2_fast(float x) {
#if __has_builtin(__builtin_amdgcn_exp2f)
    return __builtin_amdgcn_exp2f(x);
#else
    return exp2f(x);
#endif
}
__device__ __forceinline__ int pack_loc(int v) {
    return (v < 0) ? (int)(0x80000000u | (unsigned)(-v)) : v;
}
__device__ __forceinline__ float asf(int v) { return __int_as_float(v); }

// cc = sgn(y) * (cos-magnitude * scale * LOG2E)
__device__ __forceinline__ float cos_cc(int y, float k1, float k0) {
    int   x  = (y & 0x7fffffff) + 1;
    float cc = fmaf((float)__clz(x), k1, k0);
    return __int_as_float(__float_as_int(cc) ^ (y & 0x80000000));
}

__global__ __launch_bounds__(256, 2) void critigraph_kernel(
    const int*   __restrict__ cur_tar,
    const int*   __restrict__ cnc_loc,
    const int*   __restrict__ sta_loc,
    const int*   __restrict__ ttn_loc,
    const int*   __restrict__ voc_loc,
    const float* __restrict__ sta_emb,
    const float* __restrict__ ttn_emb,
    float*       __restrict__ out)
{
    __shared__ int4  s_dyn4[NTn * TPd];   // {apos, base2d, peu_bits, pad}  8KB
    __shared__ int2  s_sta2[KV * TPd];    // {apos, base2s}                 8KB
    __shared__ int   s_cnc[NC * TPd];     // packed cnc_loc
    __shared__ int   s_staloc[TPd];
    __shared__ float s_csum[Sn];
    __shared__ float s_eu[NTn];
    __shared__ float s_peu[NTn];
    __shared__ float s_dotbase[TPd];
    __shared__ float s_kl;

    const int t   = blockIdx.x;
    const int tid = threadIdx.x;

    // ---- phase 0: pack sta/cnc locations ----
    if (tid < TPd) s_staloc[tid] = pack_loc(sta_loc[t * TPd + tid]);
    for (int i = tid; i < NC * TPd; i += 256)
        s_cnc[i] = pack_loc(cnc_loc[t * NC * TPd + i]);
    __syncthreads();

    // ---- phase 1: pos tables (packed + raw cos_sp), csum via 8-lane shuffles, eu dot ----
    const int mysta = s_staloc[tid & 7];
    float mysp[6];
    #pragma unroll
    for (int k = 0; k < 6; ++k) {
        int i = tid + 256 * k;
        int s = i >> 3;
        int v = (s < NTn) ? ttn_loc[t * NTn * TPd + i]
                          : voc_loc[t * KV * TPd + (i - NTn * TPd)];
        int packed = pack_loc(v);
        int y = packed ^ mysta;
        int x = (y & 0x7fffffff) + 1;
        float c = fmaf((float)__clz(x), 0.0625f, -1.0f);   // raw cos_sp
        c = __int_as_float(__float_as_int(c) ^ (y & 0x80000000));
        mysp[k] = c;
        if (s < NTn) s_dyn4[i].x = packed;
        else         s_sta2[i - NTn * TPd].x = packed;
        float v8 = c;
        v8 += __shfl_xor(v8, 1);
        v8 += __shfl_xor(v8, 2);
        v8 += __shfl_xor(v8, 4);
        if ((tid & 7) == 0) s_csum[s] = v8;
    }
    // eu: 4 threads per row, 16 independent float4 loads each
    {
        const int r = tid >> 2, q = tid & 3;
        const float4* A = (const float4*)(sta_emb + (size_t)t * Dn);
        const float4* B = (const float4*)(ttn_emb + ((size_t)t * NTn + r) * Dn);
        float acc = 0.f;
        #pragma unroll
        for (int k = 0; k < 16; ++k) {
            float4 a = A[k * 4 + q];
            float4 b = B[k * 4 + q];
            acc += a.x * b.x + a.y * b.y + a.z * b.z + a.w * b.w;
        }
        acc += __shfl_xor(acc, 1);
        acc += __shfl_xor(acc, 2);
        if (q == 0) s_eu[r] = acc;                          // 20*TEMP = 1.0
    }
    __syncthreads();

    // ---- phase 2: final base2 tables; softmax over eu (wave 0) ----
    #pragma unroll
    for (int k = 0; k < 6; ++k) {
        int i = tid + 256 * k;
        int s = i >> 3;
        float sc = (s < NTn) ? (0.125f * LOG2E) : (2.5f * LOG2E);
        float b2 = (s_csum[s] - mysp[k]) * sc;
        if (s < NTn) s_dyn4[i].y = __float_as_int(b2);
        else         s_sta2[i - NTn * TPd].y = __float_as_int(b2);
    }
    if (tid < 64) {
        float e  = s_eu[tid];
        float mx = e;
        #pragma unroll
        for (int m = 1; m < 64; m <<= 1) mx = fmaxf(mx, __shfl_xor(mx, m));
        float ex = __expf(e - mx);
        float z  = ex;
        #pragma unroll
        for (int m = 1; m < 64; m <<= 1) z += __shfl_xor(z, m);
        float pe = ex / z;
        s_peu[tid] = pe;
        float kls = pe * ((e - mx) - __logf(z));
        #pragma unroll
        for (int m = 1; m < 64; m <<= 1) kls += __shfl_xor(kls, m);
        if (tid == 0) s_kl = kls;
    }
    __syncthreads();

    // ---- phase 3: peu into dyn table .z; dotbase[p] = sum_s peu[s]*base2d[s,p] ----
    #pragma unroll
    for (int k = 0; k < 2; ++k) {
        int i = tid + 256 * k;
        s_dyn4[i].z = __float_as_int(s_peu[i >> 3]);
    }
    if (tid < 64) {
        int g = tid & 7, j = tid >> 3;
        float a = 0.f;
        #pragma unroll
        for (int k = 0; k < 8; ++k) {
            int s = 8 * j + k;
            a = fmaf(s_peu[s], asf(s_dyn4[s * TPd + g].y), a);
        }
        #pragma unroll
        for (int m = 8; m < 64; m <<= 1) a += __shfl_xor(a, m);
        if (tid < TPd) s_dotbase[g] = a;
    }
    __syncthreads();

    // ---- phase 4: hot loop. thread-per-pair x2 (c = tid>>3 and c+32, p = tid&7) ----
    const int p     = tid & 7;
    const int acnc1 = s_cnc[tid];
    const int acnc2 = s_cnc[tid + 256];
    const int tar   = cur_tar[t];
    const float kl  = s_kl;
    const float dtb = s_dotbase[p];

    float sumA = 0.f, dotA = 0.f, sumB = 0.f, dotB = 0.f;
    #pragma unroll 16
    for (int s = 0; s < NTn; ++s) {
        int4  ab = s_dyn4[s * TPd + p];
        float bb = asf(ab.y);
        float pe = asf(ab.z);
        float ccA = cos_cc(ab.x ^ acnc1, K1D, K0D);
        sumA += exp2_fast(bb + ccA);
        dotA  = fmaf(pe, ccA, dotA);
        float ccB = cos_cc(ab.x ^ acnc2, K1D, K0D);
        sumB += exp2_fast(bb + ccB);
        dotB  = fmaf(pe, ccB, dotB);
    }
    float s2A = 0.f, s2B = 0.f;
    #pragma unroll 16
    for (int v = 0; v < KV; ++v) {
        int2  ab = s_sta2[v * TPd + p];
        float bb = asf(ab.y);
        s2A += exp2_fast(bb + cos_cc(ab.x ^ acnc1, K1S, K0S));
        s2B += exp2_fast(bb + cos_cc(ab.x ^ acnc2, K1S, K0S));
    }
    {
        int2  tt = s_sta2[tar * TPd + p];
        float bt = asf(tt.y);
        float tA = bt + cos_cc(tt.x ^ acnc1, K1S, K0S);
        float tB = bt + cos_cc(tt.x ^ acnc2, K1S, K0S);
        float* od = out + (size_t)t * NC * TPd;
        float* os = out + OUT1 + (size_t)t * NC * TPd;
        od[tid]       = kl + LN2 * (__log2f(sumA) - (dtb + dotA));
        od[tid + 256] = kl + LN2 * (__log2f(sumB) - (dtb + dotB));
        os[tid]       = LN2 * (__log2f(s2A) - tA);
        os[tid + 256] = LN2 * (__log2f(s2B) - tB);
    }

    // ---- phase 5: tail pairs (c = 64, p = 0..7): 2 per wave, 32-lane s-split ----
    {
        const int w    = tid >> 6;
        const int lane = tid & 63;
        const int half = lane >> 5;
        const int sub  = lane & 31;
        const int pt   = 2 * w + half;
        const int acnct = s_cnc[512 + pt];
        float sumd = 0.f, dotd = 0.f, sums = 0.f;
        #pragma unroll
        for (int k = 0; k < 2; ++k) {
            int4 ab = s_dyn4[(sub + 32 * k) * TPd + pt];
            float cc = cos_cc(ab.x ^ acnct, K1D, K0D);
            sumd += exp2_fast(asf(ab.y) + cc);
            dotd  = fmaf(asf(ab.z), cc, dotd);
        }
        #pragma unroll
        for (int k = 0; k < 4; ++k) {
            int2 ab = s_sta2[(sub + 32 * k) * TPd + pt];
            sums += exp2_fast(asf(ab.y) + cos_cc(ab.x ^ acnct, K1S, K0S));
        }
        #pragma unroll
        for (int m = 1; m < 32; m <<= 1) {
            sumd += __shfl_xor(sumd, m);
            dotd += __shfl_xor(dotd, m);
            sums += __shfl_xor(sums, m);
        }
        if (sub == 0) {
            int2  tt = s_sta2[tar * TPd + pt];
            float tT = asf(tt.y) + cos_cc(tt.x ^ acnct, K1S, K0S);
            out[(size_t)t * NC * TPd + 512 + pt] =
                kl + LN2 * (__log2f(sumd) - (s_dotbase[pt] + dotd));
            out[OUT1 + (size_t)t * NC * TPd + 512 + pt] =
                LN2 * (__log2f(sums) - tT);
        }
    }
}

extern "C" void kernel_launch(void* const* d_in, const int* in_sizes, int n_in,
                              void* d_out, int out_size, void* d_ws, size_t ws_size,
                              hipStream_t stream) {
    (void)in_sizes; (void)n_in; (void)d_ws; (void)ws_size; (void)out_size;
    const int*   cur_tar = (const int*)  d_in[0];
    const int*   cnc_loc = (const int*)  d_in[1];
    const int*   sta_loc = (const int*)  d_in[2];
    const int*   ttn_loc = (const int*)  d_in[3];
    const int*   voc_loc = (const int*)  d_in[4];
    const float* sta_emb = (const float*)d_in[5];
    const float* ttn_emb = (const float*)d_in[6];
    // d_in[7] (voc_emb) intentionally unused: it only feeds eu_val[:,64:], discarded.
    critigraph_kernel<<<Tn, 256, 0, stream>>>(cur_tar, cnc_loc, sta_loc, ttn_loc,
                                              voc_loc, sta_emb, ttn_emb, (float*)d_out);
}